// Round 12
// baseline (2497.738 us; speedup 1.0000x reference)
//
#include <hip/hip_runtime.h>
#include <math.h>

#define B_ 32
#define S_ 128
#define H_ 512
#define V_ 32000
#define G4_ 2048
#define NVT 2000        // W_out 16-col v-tiles
#define NWT 1000        // gemm wave-tiles (32 cols each)
#define RBLK 64         // recurrence blocks (n-chunks of 8)
#define GBLK 250        // gemm blocks (4 waves x 32 cols = 128 cols each)

typedef __attribute__((ext_vector_type(8))) short bf8;   // 8 x bf16 fragment
typedef __attribute__((ext_vector_type(4))) float f4;    // MFMA accumulator
typedef __attribute__((ext_vector_type(4))) unsigned u32x4;  // native vec for asm "v"
typedef unsigned short us;

__device__ __forceinline__ us f2bf(float x) {
    union { float f; unsigned u; } v; v.f = x;
    unsigned r = v.u + 0x7FFFu + ((v.u >> 16) & 1u);     // RNE
    return (us)(r >> 16);
}
__device__ __forceinline__ float bf2f(us b) {
    union { unsigned u; float f; } v; v.u = ((unsigned)b) << 16; return v.f;
}
__device__ __forceinline__ float4 ldf4(const float* p) {
    return *reinterpret_cast<const float4*>(p);
}
// 16B store with sc0+sc1: write-through past L2 to the coherence point (L3)
__device__ __forceinline__ void store16_sc(void* gaddr, u32x4 d) {
    asm volatile("global_store_dwordx4 %0, %1, off sc0 sc1"
                 :: "v"(gaddr), "v"(d) : "memory");
}

// ------ split W_out into bf16 hi/lo, pre-swizzled to MFMA B-fragment order (once) ----
__global__ __launch_bounds__(256) void k_wsplit(const float* __restrict__ W,
                                                us* __restrict__ Wph,
                                                us* __restrict__ Wpl) {
    const size_t id = (size_t)blockIdx.x * 256 + threadIdx.x;   // 0 .. NVT*16*64-1
    const int lane = (int)(id & 63);
    const size_t fc = id >> 6;            // vt*16 + kc
    const int kc = (int)(fc & 15);
    const size_t vt = fc >> 4;
    const size_t r = vt * 16 + (lane & 15);
    const int k0 = kc * 32 + (lane >> 4) * 8;
    const float* src = W + r * H_ + k0;
    bf8 hv, lv;
#pragma unroll
    for (int e = 0; e < 8; ++e) {
        float x = src[e];
        us hb = f2bf(x);
        hv[e] = (short)hb;
        lv[e] = (short)f2bf(x - bf2f(hb));
    }
    *reinterpret_cast<bf8*>(Wph + id * 8) = hv;
    *reinterpret_cast<bf8*>(Wpl + id * 8) = lv;
}

// ------ split W_hh into THREE bf16 levels, B-fragment order grouped per recur block ---
__global__ __launch_bounds__(256) void k_whh3(const float* __restrict__ W,
                                              us* __restrict__ B1,
                                              us* __restrict__ B2,
                                              us* __restrict__ B3) {
    const size_t id = (size_t)blockIdx.x * 256 + threadIdx.x;  // ((g*2+nt)*16+kc)*64+lane
    const int lane = (int)(id & 63);
    const size_t fc = id >> 6;
    const int kc = (int)(fc & 15);
    const size_t gt = fc >> 4;
    const int nt = (int)(gt & 1);
    const int g = (int)(gt >> 1);
    const int c = lane & 15;
    const int q = nt * 2 + (c >> 3), nl = c & 7;
    const int row = q * 512 + g * 8 + nl;
    const int k0 = kc * 32 + (lane >> 4) * 8;
    const float* src = W + (size_t)row * H_ + k0;
    bf8 v1, v2, v3;
#pragma unroll
    for (int e = 0; e < 8; ++e) {
        float x = src[e];
        us a1 = f2bf(x);
        float r1 = x - bf2f(a1);
        us a2 = f2bf(r1);
        float r2 = r1 - bf2f(a2);
        v1[e] = (short)a1; v2[e] = (short)a2; v3[e] = (short)f2bf(r2);
    }
    *reinterpret_cast<bf8*>(B1 + id * 8) = v1;
    *reinterpret_cast<bf8*>(B2 + id * 8) = v2;
    *reinterpret_cast<bf8*>(B3 + id * 8) = v3;
}

// ------- precompute XW[t][b][j] = emb[tok[b,t]] @ W_ih^T + b_ih + b_hh (once) -------
__global__ __launch_bounds__(256) void k_xw(const int* __restrict__ inputs,
                                            const float* __restrict__ emb,
                                            const float* __restrict__ W_ih,
                                            const float* __restrict__ b_ih,
                                            const float* __restrict__ b_hh,
                                            float* __restrict__ XW) {
    __shared__ float es[16 * H_];
    const int tid = threadIdx.x;
    const int j = blockIdx.x * 256 + tid;
    const int t = blockIdx.y;
    const float bias = b_ih[j] + b_hh[j];
#pragma unroll
    for (int half = 0; half < 2; ++half) {
        __syncthreads();
        for (int idx = tid; idx < 16 * 128; idx += 256) {
            int b = idx >> 7, k4 = (idx & 127) << 2;
            int tok = inputs[(half * 16 + b) * S_ + t];
            *reinterpret_cast<float4*>(&es[b * H_ + k4]) = ldf4(emb + (size_t)tok * H_ + k4);
        }
        __syncthreads();
        float acc[16];
#pragma unroll
        for (int b = 0; b < 16; ++b) acc[b] = 0.f;
        for (int k = 0; k < H_; k += 4) {
            float4 wv = ldf4(W_ih + (size_t)j * H_ + k);
#pragma unroll
            for (int b = 0; b < 16; ++b) {
                float4 xv = *reinterpret_cast<const float4*>(&es[b * H_ + k]);
                acc[b] += wv.x * xv.x + wv.y * xv.y + wv.z * xv.z + wv.w * xv.w;
            }
        }
#pragma unroll
        for (int b = 0; b < 16; ++b)
            XW[(size_t)(t * B_ + half * 16 + b) * G4_ + j] = acc[b] + bias;
    }
}

// ========= THE FAT KERNEL: recur (blk<64) + gemm (64<=blk<314) + aggregator ==========
__global__ __launch_bounds__(256, 2)
void k_fat(const int* __restrict__ inputs,
           const float* __restrict__ h0, const float* __restrict__ c0,
           const us* __restrict__ B1f, const us* __restrict__ B2f,
           const us* __restrict__ B3f, const float* __restrict__ XW,
           us* __restrict__ A1, us* __restrict__ A2, us* __restrict__ A3,
           const us* __restrict__ Wph, const us* __restrict__ Wpl,
           const float* __restrict__ b_out, float* __restrict__ sp,
           int* __restrict__ flags) {
    __shared__ us wl3[16384];          // 32 KB: B3 fragments (recur role only)
    __shared__ float glds[32][33];     // gates exchange (recur role only)
    const int blk = blockIdx.x, tid = threadIdx.x;
    const int lane = tid & 63;
    int* const gstep = flags + RBLK * 32;    // single aggregated step counter

    if (blk < RBLK) {
        // ---------------------------- RECURRENCE ROLE ----------------------------
        const int g = blk;
        const int wv = tid >> 6;
        const int mt = wv >> 1, nt = wv & 1;
        // B1/B2 slices -> pinned registers (wave-specific nt slice)
        bf8 B1r[16], B2r[16];
#pragma unroll
        for (int kc = 0; kc < 16; ++kc) {
            const size_t o = ((size_t)(g * 2 + nt) * 16 + kc) * 512 + lane * 8;
            B1r[kc] = *reinterpret_cast<const bf8*>(B1f + o);
            B2r[kc] = *reinterpret_cast<const bf8*>(B2f + o);
        }
#pragma unroll
        for (int kc = 0; kc < 16; ++kc)
            asm volatile("" : "+v"(B1r[kc]), "+v"(B2r[kc]));
        // B3 slice -> LDS
        {
            const size_t base = (size_t)g * 16384;
            for (int i = tid; i < 2048; i += 256)
                reinterpret_cast<u32x4*>(wl3)[i] =
                    reinterpret_cast<const u32x4*>(B3f + base)[i];
        }
        // cell identity
        const int b = tid >> 3, nl = tid & 7;
        const int n = g * 8 + nl;
        const int kc_w = g >> 2, kg_w = g & 3, half_w = b >> 4,
                  lane_w = kg_w * 16 + (b & 15);
        float c_reg = c0[b * H_ + n];
        float hn = h0[b * H_ + n];
        const int lb = lane & 56;

        auto publish = [&](int slot, float h) {
            us a1 = f2bf(h);
            float r1 = h - bf2f(a1);
            us a2 = f2bf(r1);
            us a3 = f2bf(r1 - bf2f(a2));
            unsigned p1 = ((unsigned)a1 & 0xffffu) |
                          (((unsigned)(us)__shfl_xor((int)a1, 1)) << 16);
            unsigned p2 = ((unsigned)a2 & 0xffffu) |
                          (((unsigned)(us)__shfl_xor((int)a2, 1)) << 16);
            unsigned p3 = ((unsigned)a3 & 0xffffu) |
                          (((unsigned)(us)__shfl_xor((int)a3, 1)) << 16);
            u32x4 d1, d2, d3;
            d1[0] = p1; d1[1] = (unsigned)__shfl((int)p1, lb + 2);
            d1[2] = (unsigned)__shfl((int)p1, lb + 4); d1[3] = (unsigned)__shfl((int)p1, lb + 6);
            d2[0] = p2; d2[1] = (unsigned)__shfl((int)p2, lb + 2);
            d2[2] = (unsigned)__shfl((int)p2, lb + 4); d2[3] = (unsigned)__shfl((int)p2, lb + 6);
            d3[0] = p3; d3[1] = (unsigned)__shfl((int)p3, lb + 2);
            d3[2] = (unsigned)__shfl((int)p3, lb + 4); d3[3] = (unsigned)__shfl((int)p3, lb + 6);
            if (nl == 0) {
                const size_t ix =
                    ((((size_t)slot * 16 + kc_w) * 2 + half_w) * 64 + lane_w) * 8;
                store16_sc(A1 + ix, d1);
                store16_sc(A2 + ix, d2);
                store16_sc(A3 + ix, d3);
            }
        };
        publish(0, hn);                                    // slot 0 = h_{-1} = h0
        asm volatile("s_waitcnt vmcnt(0)" ::: "memory");   // data at L3
        __syncthreads();
        if (tid == 0)
            __hip_atomic_store(&flags[g * 32], 1, __ATOMIC_RELAXED,
                               __HIP_MEMORY_SCOPE_AGENT);

        const int cidx = lane & 15;
        for (int t = 0; t < S_; ++t) {
            // prefetch XW[t] (h-independent) before the wait
            const float* xwp = XW + ((size_t)t * B_ + b) * G4_;
            float xw0 = xwp[n], xw1 = xwp[512 + n], xw2 = xwp[1024 + n],
                  xw3 = xwp[1536 + n];
            if (tid < 64) {
                int spins = 0;
                while (__hip_atomic_load(&flags[tid * 32], __ATOMIC_RELAXED,
                                         __HIP_MEMORY_SCOPE_AGENT) < t + 1) {
                    __builtin_amdgcn_s_sleep(1);
                    if (++spins > (1 << 18)) break;
                }
            }
            __syncthreads();
            // 6-term MFMA, 3 accumulators (break serial chain)
            f4 aA = {0.f, 0.f, 0.f, 0.f}, aB = {0.f, 0.f, 0.f, 0.f},
               aC = {0.f, 0.f, 0.f, 0.f};
            const us* a1p = A1 + ((((size_t)t * 16) * 2 + mt) * 64 + lane) * 8;
            const us* a2p = A2 + ((((size_t)t * 16) * 2 + mt) * 64 + lane) * 8;
            const us* a3p = A3 + ((((size_t)t * 16) * 2 + mt) * 64 + lane) * 8;
            const us* b3p = wl3 + ((size_t)(nt * 16) * 64 + lane) * 8;
#pragma unroll
            for (int kc = 0; kc < 16; ++kc) {
                bf8 A1v = *reinterpret_cast<const bf8*>(a1p + (size_t)kc * 1024);
                bf8 A2v = *reinterpret_cast<const bf8*>(a2p + (size_t)kc * 1024);
                bf8 A3v = *reinterpret_cast<const bf8*>(a3p + (size_t)kc * 1024);
                bf8 B3v = *reinterpret_cast<const bf8*>(b3p + (size_t)kc * 512);
                aA = __builtin_amdgcn_mfma_f32_16x16x32_bf16(A1v, B1r[kc], aA, 0, 0, 0);
                aB = __builtin_amdgcn_mfma_f32_16x16x32_bf16(A1v, B2r[kc], aB, 0, 0, 0);
                aA = __builtin_amdgcn_mfma_f32_16x16x32_bf16(A2v, B2r[kc], aA, 0, 0, 0);
                aB = __builtin_amdgcn_mfma_f32_16x16x32_bf16(A2v, B1r[kc], aB, 0, 0, 0);
                aC = __builtin_amdgcn_mfma_f32_16x16x32_bf16(A1v, B3v, aC, 0, 0, 0);
                aC = __builtin_amdgcn_mfma_f32_16x16x32_bf16(A3v, B1r[kc], aC, 0, 0, 0);
            }
            f4 acc = aA + aB;
            acc = acc + aC;
#pragma unroll
            for (int r = 0; r < 4; ++r)
                glds[mt * 16 + (lane >> 4) * 4 + r][nt * 16 + cidx] = acc[r];
            __syncthreads();
            // cell
            const float s_i = glds[b][nl]      + xw0;
            const float s_f = glds[b][8 + nl]  + xw1;
            const float s_g = glds[b][16 + nl] + xw2;
            const float s_o = glds[b][24 + nl] + xw3;
            const float ig = 1.f / (1.f + expf(-s_i));
            const float fg = 1.f / (1.f + expf(-s_f));
            const float gg = tanhf(s_g);
            const float og = 1.f / (1.f + expf(-s_o));
            c_reg = fg * c_reg + ig * gg;
            hn = og * tanhf(c_reg);
            publish(t + 1, hn);
            asm volatile("s_waitcnt vmcnt(0)" ::: "memory");
            __syncthreads();
            if (tid == 0)
                __hip_atomic_store(&flags[g * 32], t + 2, __ATOMIC_RELAXED,
                                   __HIP_MEMORY_SCOPE_AGENT);
        }
    } else if (blk < RBLK + GBLK) {
        // ------------------------------ GEMM ROLE --------------------------------
        const int wv = tid >> 6;
        const int wt = (blk - RBLK) * 4 + wv;           // 0..999, 32 cols each
        if (wt >= NWT) return;
        const int col0 = wt * 32;
        const size_t vt0 = (size_t)wt * 2, vt1 = vt0 + 1;
        // Wh for both 16-col tiles -> pinned registers (128 VGPR)
        bf8 Bh0[16], Bh1[16];
#pragma unroll
        for (int kc = 0; kc < 16; ++kc) {
            Bh0[kc] = *reinterpret_cast<const bf8*>(Wph + ((vt0 * 16 + kc) * 64 + lane) * 8);
            Bh1[kc] = *reinterpret_cast<const bf8*>(Wph + ((vt1 * 16 + kc) * 64 + lane) * 8);
        }
#pragma unroll
        for (int kc = 0; kc < 16; ++kc)
            asm volatile("" : "+v"(Bh0[kc]), "+v"(Bh1[kc]));
        const float bo0 = b_out[col0 + (lane & 15)];
        const float bo1 = b_out[col0 + 16 + (lane & 15)];
        const int g16 = lane >> 4;

        for (int mt = 0; mt < S_; ++mt) {
            // pace on the aggregated counter: single cacheline, lane 0 only
            if (lane == 0) {
                int spins = 0;
                while (__hip_atomic_load(gstep, __ATOMIC_RELAXED,
                                         __HIP_MEMORY_SCOPE_AGENT) < mt + 2) {
                    __builtin_amdgcn_s_sleep(16);
                    if (++spins > (1 << 18)) break;
                }
            }
            f4 a00 = {0.f,0.f,0.f,0.f}, a01 = {0.f,0.f,0.f,0.f};
            f4 a10 = {0.f,0.f,0.f,0.f}, a11 = {0.f,0.f,0.f,0.f};
#pragma unroll
            for (int kc = 0; kc < 16; ++kc) {
                const size_t ab = ((((size_t)(mt + 1) * 16 + kc) * 2) * 64 + lane) * 8;
                bf8 A0h = *reinterpret_cast<const bf8*>(A1 + ab);
                bf8 A1h = *reinterpret_cast<const bf8*>(A1 + ab + 512);
                bf8 A0l = *reinterpret_cast<const bf8*>(A2 + ab);
                bf8 A1l = *reinterpret_cast<const bf8*>(A2 + ab + 512);
                bf8 Wl0 = *reinterpret_cast<const bf8*>(Wpl + ((vt0 * 16 + kc) * 64 + lane) * 8);
                bf8 Wl1 = *reinterpret_cast<const bf8*>(Wpl + ((vt1 * 16 + kc) * 64 + lane) * 8);
                a00 = __builtin_amdgcn_mfma_f32_16x16x32_bf16(A0h, Bh0[kc], a00, 0, 0, 0);
                a01 = __builtin_amdgcn_mfma_f32_16x16x32_bf16(A1h, Bh0[kc], a01, 0, 0, 0);
                a10 = __builtin_amdgcn_mfma_f32_16x16x32_bf16(A0h, Bh1[kc], a10, 0, 0, 0);
                a11 = __builtin_amdgcn_mfma_f32_16x16x32_bf16(A1h, Bh1[kc], a11, 0, 0, 0);
                a00 = __builtin_amdgcn_mfma_f32_16x16x32_bf16(A0l, Bh0[kc], a00, 0, 0, 0);
                a01 = __builtin_amdgcn_mfma_f32_16x16x32_bf16(A1l, Bh0[kc], a01, 0, 0, 0);
                a10 = __builtin_amdgcn_mfma_f32_16x16x32_bf16(A0l, Bh1[kc], a10, 0, 0, 0);
                a11 = __builtin_amdgcn_mfma_f32_16x16x32_bf16(A1l, Bh1[kc], a11, 0, 0, 0);
                a00 = __builtin_amdgcn_mfma_f32_16x16x32_bf16(A0h, Wl0, a00, 0, 0, 0);
                a01 = __builtin_amdgcn_mfma_f32_16x16x32_bf16(A1h, Wl0, a01, 0, 0, 0);
                a10 = __builtin_amdgcn_mfma_f32_16x16x32_bf16(A0h, Wl1, a10, 0, 0, 0);
                a11 = __builtin_amdgcn_mfma_f32_16x16x32_bf16(A1h, Wl1, a11, 0, 0, 0);
            }
            // wave-local softmax/argmax/target partials (no LDS, no barriers)
            const int tokreg = inputs[(lane & 31) * S_ + mt];
            const int c0a = col0 + (lane & 15), c1a = c0a + 16;
#pragma unroll
            for (int h = 0; h < 2; ++h) {
#pragma unroll
                for (int r = 0; r < 4; ++r) {
                    float x0 = (h ? a01[r] : a00[r]) + bo0;
                    float x1 = (h ? a11[r] : a10[r]) + bo1;
                    const int bb = h * 16 + g16 * 4 + r;
                    const int tok = __shfl(tokreg, bb);
                    float m; int mi;
                    if (x1 > x0) { m = x1; mi = c1a; } else { m = x0; mi = c0a; }
                    float s = __expf(x0 - m) + __expf(x1 - m);
                    float tv = fmaxf(c0a == tok ? x0 : -INFINITY,
                                     c1a == tok ? x1 : -INFINITY);
#pragma unroll
                    for (int off = 1; off < 16; off <<= 1) {
                        float cm = __shfl_xor(m, off), cs = __shfl_xor(s, off);
                        float ctv = __shfl_xor(tv, off);
                        int cmi = __shfl_xor(mi, off);
                        float nm = fmaxf(m, cm);
                        s = s * __expf(m - nm) + cs * __expf(cm - nm);
                        if (cm > m || (cm == m && cmi < mi)) mi = cmi;
                        m = nm;
                        tv = fmaxf(tv, ctv);
                    }
                    if ((lane & 15) == 0) {
                        float4 e = {m, s, (float)mi, tv};
                        *reinterpret_cast<float4*>(
                            sp + ((size_t)(mt * 32 + bb) * NWT + wt) * 4) = e;
                    }
                }
            }
        }
    } else {
        // --------------------------- AGGREGATOR ROLE -----------------------------
        // one wave folds the 64 per-block flags into the single gstep counter
        if (tid < 64) {
            int cur = 1;
            long spins = 0;
            while (cur <= S_ + 1) {
                int f = __hip_atomic_load(&flags[tid * 32], __ATOMIC_RELAXED,
                                          __HIP_MEMORY_SCOPE_AGENT);
                if (__all(f >= cur)) {
                    if (tid == 0)
                        __hip_atomic_store(gstep, cur, __ATOMIC_RELAXED,
                                           __HIP_MEMORY_SCOPE_AGENT);
                    ++cur;
                } else {
                    __builtin_amdgcn_s_sleep(2);
                }
                if (++spins > (1l << 24)) break;   // safety valve
            }
        }
    }
}

// ---------------- merge 1000 wave-tile partials per row -> symbols + logp ----------
__global__ __launch_bounds__(256) void k_merge(const float* __restrict__ sp,
                                               float* __restrict__ out,
                                               float* __restrict__ lossbuf) {
    const int tid = threadIdx.x;
    const int row16 = tid >> 4, l16 = tid & 15;
    const int m_ = blockIdx.x * 16 + row16;            // mt*32 + b
    float mm = -INFINITY, s = 0.f, amv = -INFINITY, tv = -INFINITY;
    int ami = 0x7fffffff;
    for (int i = l16; i < NWT; i += 16) {
        const float4 e = *reinterpret_cast<const float4*>(sp + ((size_t)m_ * NWT + i) * 4);
        const float cm = e.x, cs = e.y, ctv = e.w;
        const int cmi = (int)e.z;
        float nm = fmaxf(mm, cm);
        s = s * expf(mm - nm) + cs * expf(cm - nm);
        mm = nm;
        if (cm > amv || (cm == amv && cmi < ami)) { amv = cm; ami = cmi; }
        tv = fmaxf(tv, ctv);
    }
#pragma unroll
    for (int off = 1; off < 16; off <<= 1) {
        float cm = __shfl_xor(mm, off), cs = __shfl_xor(s, off);
        float camv = __shfl_xor(amv, off), ctv = __shfl_xor(tv, off);
        int cmi = __shfl_xor(ami, off);
        float nm = fmaxf(mm, cm);
        s = s * expf(mm - nm) + cs * expf(cm - nm);
        mm = nm;
        if (camv > amv || (camv == amv && cmi < ami)) { amv = camv; ami = cmi; }
        tv = fmaxf(tv, ctv);
    }
    if (l16 == 0) {
        const float logZ = mm + logf(s);
        const int t = m_ >> 5, b = m_ & 31;
        out[1 + b * S_ + t] = (float)ami;
        lossbuf[m_] = tv - logZ;
    }
}

// ---------------- final: deterministic sum of per-row losses ----------------
__global__ __launch_bounds__(256) void k_sum(const float* __restrict__ lossbuf,
                                             float* __restrict__ out) {
    const int tid = threadIdx.x;
    float a = 0.f;
    for (int i = tid; i < B_ * S_; i += 256) a += lossbuf[i];
    __shared__ float red[256];
    red[tid] = a;
    __syncthreads();
    for (int off = 128; off > 0; off >>= 1) {
        if (tid < off) red[tid] += red[tid + off];
        __syncthreads();
    }
    if (tid == 0) out[0] = -red[0] / (float)B_;
}

extern "C" void kernel_launch(void* const* d_in, const int* in_sizes, int n_in,
                              void* d_out, int out_size, void* d_ws, size_t ws_size,
                              hipStream_t stream) {
    const int*   inputs = (const int*)d_in[0];
    const float* h0     = (const float*)d_in[3];
    const float* c0     = (const float*)d_in[4];
    const float* emb    = (const float*)d_in[5];
    const float* W_ih   = (const float*)d_in[6];
    const float* W_hh   = (const float*)d_in[7];
    const float* b_ih   = (const float*)d_in[8];
    const float* b_hh   = (const float*)d_in[9];
    const float* W_out  = (const float*)d_in[10];
    const float* b_out  = (const float*)d_in[11];
    float* out = (float*)d_out;

    char* p = (char*)d_ws;
    auto alloc = [&](size_t bytes) { char* r = p; p += (bytes + 255) & ~255ull; return r; };
    float* lossbuf  = (float*)alloc((size_t)B_ * S_ * 4);
    int*   flags    = (int*)alloc((RBLK * 32 + 64) * 4);                     // + gstep line
    float* sp       = (float*)alloc((size_t)B_ * S_ * NWT * 4 * 4);          // 65.5 MB
    us* A1  = (us*)alloc((size_t)(S_ + 1) * 16384 * 2);
    us* A2  = (us*)alloc((size_t)(S_ + 1) * 16384 * 2);
    us* A3  = (us*)alloc((size_t)(S_ + 1) * 16384 * 2);
    us* Wph = (us*)alloc((size_t)NVT * 16 * 64 * 8 * 2);                     // 32.8 MB
    us* Wpl = (us*)alloc((size_t)NVT * 16 * 64 * 8 * 2);
    us* B1f = (us*)alloc((size_t)RBLK * 16384 * 2);                          // 2.1 MB
    us* B2f = (us*)alloc((size_t)RBLK * 16384 * 2);
    us* B3f = (us*)alloc((size_t)RBLK * 16384 * 2);
    float* XW = (float*)alloc((size_t)S_ * B_ * G4_ * 4);                    // 33.5 MB

    (void)hipMemsetAsync(flags, 0, (RBLK * 32 + 64) * 4, stream);
    k_wsplit<<<(NVT * 16 * 64) / 256, 256, 0, stream>>>(W_out, Wph, Wpl);
    k_whh3<<<(RBLK * 2 * 16 * 64) / 256, 256, 0, stream>>>(W_hh, B1f, B2f, B3f);
    k_xw<<<dim3(8, S_), 256, 0, stream>>>(inputs, emb, W_ih, b_ih, b_hh, XW);
    k_fat<<<RBLK + GBLK + 1, 256, 0, stream>>>(inputs, h0, c0, B1f, B2f, B3f, XW,
                                               A1, A2, A3, Wph, Wpl, b_out, sp, flags);
    k_merge<<<(B_ * S_) / 16, 256, 0, stream>>>(sp, out, lossbuf);
    k_sum<<<1, 256, 0, stream>>>(lossbuf, out);
}

// Round 13
// 1892.523 us; speedup vs baseline: 1.3198x; 1.3198x over previous
//
#include <hip/hip_runtime.h>
#include <math.h>

#define B_ 32
#define S_ 128
#define H_ 512
#define V_ 32000
#define G4_ 2048
#define NVT 2000        // W_out 16-col v-tiles
#define NGB 500         // gemm blocks (64 cols each)
#define RBLK 64         // recurrence blocks (n-chunks of 8)

typedef __attribute__((ext_vector_type(8))) short bf8;   // 8 x bf16 fragment
typedef __attribute__((ext_vector_type(4))) float f4;    // MFMA accumulator
typedef unsigned short us;

__device__ __forceinline__ us f2bf(float x) {
    union { float f; unsigned u; } v; v.f = x;
    unsigned r = v.u + 0x7FFFu + ((v.u >> 16) & 1u);     // RNE
    return (us)(r >> 16);
}
__device__ __forceinline__ float bf2f(us b) {
    union { unsigned u; float f; } v; v.u = ((unsigned)b) << 16; return v.f;
}
__device__ __forceinline__ float4 ldf4(const float* p) {
    return *reinterpret_cast<const float4*>(p);
}
__device__ __forceinline__ void gload_lds16(const void* g, void* l) {
    __builtin_amdgcn_global_load_lds((const __attribute__((address_space(1))) unsigned*)g,
                                     (__attribute__((address_space(3))) unsigned*)l, 16, 0, 0);
}

// ------ split W_out into bf16 hi/lo, pre-swizzled to MFMA B-fragment order (once) ----
__global__ __launch_bounds__(256) void k_wsplit(const float* __restrict__ W,
                                                us* __restrict__ Wph,
                                                us* __restrict__ Wpl) {
    const size_t id = (size_t)blockIdx.x * 256 + threadIdx.x;   // 0 .. NVT*16*64-1
    const int lane = (int)(id & 63);
    const size_t fc = id >> 6;            // vt*16 + kc
    const int kc = (int)(fc & 15);
    const size_t vt = fc >> 4;
    const size_t r = vt * 16 + (lane & 15);
    const int k0 = kc * 32 + (lane >> 4) * 8;
    const float* src = W + r * H_ + k0;
    bf8 hv, lv;
#pragma unroll
    for (int e = 0; e < 8; ++e) {
        float x = src[e];
        us hb = f2bf(x);
        hv[e] = (short)hb;
        lv[e] = (short)f2bf(x - bf2f(hb));
    }
    *reinterpret_cast<bf8*>(Wph + id * 8) = hv;
    *reinterpret_cast<bf8*>(Wpl + id * 8) = lv;
}

// ------ split W_hh into THREE bf16 levels, B-fragment order grouped per recur block ---
__global__ __launch_bounds__(256) void k_whh3(const float* __restrict__ W,
                                              us* __restrict__ B1,
                                              us* __restrict__ B2,
                                              us* __restrict__ B3) {
    const size_t id = (size_t)blockIdx.x * 256 + threadIdx.x;  // ((g*2+nt)*16+kc)*64+lane
    const int lane = (int)(id & 63);
    const size_t fc = id >> 6;
    const int kc = (int)(fc & 15);
    const size_t gt = fc >> 4;
    const int nt = (int)(gt & 1);
    const int g = (int)(gt >> 1);
    const int c = lane & 15;
    const int q = nt * 2 + (c >> 3), nl = c & 7;
    const int row = q * 512 + g * 8 + nl;
    const int k0 = kc * 32 + (lane >> 4) * 8;
    const float* src = W + (size_t)row * H_ + k0;
    bf8 v1, v2, v3;
#pragma unroll
    for (int e = 0; e < 8; ++e) {
        float x = src[e];
        us a1 = f2bf(x);
        float r1 = x - bf2f(a1);
        us a2 = f2bf(r1);
        float r2 = r1 - bf2f(a2);
        v1[e] = (short)a1; v2[e] = (short)a2; v3[e] = (short)f2bf(r2);
    }
    *reinterpret_cast<bf8*>(B1 + id * 8) = v1;
    *reinterpret_cast<bf8*>(B2 + id * 8) = v2;
    *reinterpret_cast<bf8*>(B3 + id * 8) = v3;
}

// ------- precompute XW[t][b][j] = emb[tok[b,t]] @ W_ih^T + b_ih + b_hh (once) -------
__global__ __launch_bounds__(256) void k_xw(const int* __restrict__ inputs,
                                            const float* __restrict__ emb,
                                            const float* __restrict__ W_ih,
                                            const float* __restrict__ b_ih,
                                            const float* __restrict__ b_hh,
                                            float* __restrict__ XW) {
    __shared__ float es[16 * H_];
    const int tid = threadIdx.x;
    const int j = blockIdx.x * 256 + tid;
    const int t = blockIdx.y;
    const float bias = b_ih[j] + b_hh[j];
#pragma unroll
    for (int half = 0; half < 2; ++half) {
        __syncthreads();
        for (int idx = tid; idx < 16 * 128; idx += 256) {
            int b = idx >> 7, k4 = (idx & 127) << 2;
            int tok = inputs[(half * 16 + b) * S_ + t];
            *reinterpret_cast<float4*>(&es[b * H_ + k4]) = ldf4(emb + (size_t)tok * H_ + k4);
        }
        __syncthreads();
        float acc[16];
#pragma unroll
        for (int b = 0; b < 16; ++b) acc[b] = 0.f;
        for (int k = 0; k < H_; k += 4) {
            float4 wv = ldf4(W_ih + (size_t)j * H_ + k);
#pragma unroll
            for (int b = 0; b < 16; ++b) {
                float4 xv = *reinterpret_cast<const float4*>(&es[b * H_ + k]);
                acc[b] += wv.x * xv.x + wv.y * xv.y + wv.z * xv.z + wv.w * xv.w;
            }
        }
#pragma unroll
        for (int b = 0; b < 16; ++b)
            XW[(size_t)(t * B_ + half * 16 + b) * G4_ + j] = acc[b] + bias;
    }
}

// ---------------- the MFMA recurrence: 64 blocks, fence-free flag sync (R9) ----------
__global__ __launch_bounds__(256)
void k_recur(const float* __restrict__ h0, const float* __restrict__ c0,
             const us* __restrict__ B1f, const us* __restrict__ B2f,
             const us* __restrict__ B3f, const float* __restrict__ XW,
             us* __restrict__ A1, us* __restrict__ A2,
             us* __restrict__ A3, int* __restrict__ flags) {
    __shared__ us wl1[16384], wl2[16384], wl3[16384];   // 3 x 32 KB
    __shared__ float glds[32][33];                      // gates exchange
    const int g = blockIdx.x, tid = threadIdx.x;

    // load this block's W_hh fragments into LDS (once)
    {
        const size_t base = (size_t)g * 16384;
        for (int i = tid; i < 2048; i += 256) {
            reinterpret_cast<uint4*>(wl1)[i] = reinterpret_cast<const uint4*>(B1f + base)[i];
            reinterpret_cast<uint4*>(wl2)[i] = reinterpret_cast<const uint4*>(B2f + base)[i];
            reinterpret_cast<uint4*>(wl3)[i] = reinterpret_cast<const uint4*>(B3f + base)[i];
        }
    }
    // cell-thread identity: (b, nl); n = g*8+nl owned forever (c stays in a register)
    const int b = tid >> 3, nl = tid & 7;
    const int n = g * 8 + nl;
    const int kc_w = g >> 2, kg_w = g & 3, half_w = b >> 4, lane_w = kg_w * 16 + (b & 15);
    float c_reg = c0[b * H_ + n];
    float hn = h0[b * H_ + n];

    auto write_frags = [&](int slot, float h) {
        us a1 = f2bf(h);
        float r1 = h - bf2f(a1);
        us a2 = f2bf(r1);
        us a3 = f2bf(r1 - bf2f(a2));
        unsigned v1 = a1, v2 = a2, v3 = a3;
        unsigned q1 = (unsigned)__shfl_xor((int)v1, 1);
        unsigned q2 = (unsigned)__shfl_xor((int)v2, 1);
        unsigned q3 = (unsigned)__shfl_xor((int)v3, 1);
        if ((nl & 1) == 0) {
            const size_t ix = ((((size_t)slot * 16 + kc_w) * 2 + half_w) * 64 + lane_w) * 8 + nl;
            __hip_atomic_store((unsigned*)(A1 + ix), v1 | (q1 << 16),
                               __ATOMIC_RELAXED, __HIP_MEMORY_SCOPE_AGENT);
            __hip_atomic_store((unsigned*)(A2 + ix), v2 | (q2 << 16),
                               __ATOMIC_RELAXED, __HIP_MEMORY_SCOPE_AGENT);
            __hip_atomic_store((unsigned*)(A3 + ix), v3 | (q3 << 16),
                               __ATOMIC_RELAXED, __HIP_MEMORY_SCOPE_AGENT);
        }
    };
    write_frags(0, hn);          // slot 0 = h_{-1} = h0
    asm volatile("s_waitcnt vmcnt(0)" ::: "memory");   // stores acked at L3
    __syncthreads();
    if (tid == 0)
        __hip_atomic_store(&flags[g * 32], 1, __ATOMIC_RELAXED, __HIP_MEMORY_SCOPE_AGENT);

    // wave roles for the MFMA phase
    const int wv = tid >> 6, lane = tid & 63;
    const int mt = wv >> 1, nt = wv & 1;
    const int cidx = lane & 15;

    for (int t = 0; t < S_; ++t) {
        if (tid < 64) {
            int spins = 0;
            while (__hip_atomic_load(&flags[tid * 32], __ATOMIC_RELAXED,
                                     __HIP_MEMORY_SCOPE_AGENT) < t + 1) {
                __builtin_amdgcn_s_sleep(1);
                if (++spins > (1 << 18)) break;
            }
        }
        __syncthreads();
        f4 acc = {0.f, 0.f, 0.f, 0.f};
        const us* a1p = A1 + ((((size_t)t * 16) * 2 + mt) * 64 + lane) * 8;
        const us* a2p = A2 + ((((size_t)t * 16) * 2 + mt) * 64 + lane) * 8;
        const us* a3p = A3 + ((((size_t)t * 16) * 2 + mt) * 64 + lane) * 8;
        const us* b1p = wl1 + ((size_t)(nt * 16) * 64 + lane) * 8;
        const us* b2p = wl2 + ((size_t)(nt * 16) * 64 + lane) * 8;
        const us* b3p = wl3 + ((size_t)(nt * 16) * 64 + lane) * 8;
#pragma unroll 4
        for (int kc = 0; kc < 16; ++kc) {
            bf8 A1v = *reinterpret_cast<const bf8*>(a1p + (size_t)kc * 1024);
            bf8 A2v = *reinterpret_cast<const bf8*>(a2p + (size_t)kc * 1024);
            bf8 A3v = *reinterpret_cast<const bf8*>(a3p + (size_t)kc * 1024);
            bf8 B1v = *reinterpret_cast<const bf8*>(b1p + (size_t)kc * 512);
            bf8 B2v = *reinterpret_cast<const bf8*>(b2p + (size_t)kc * 512);
            bf8 B3v = *reinterpret_cast<const bf8*>(b3p + (size_t)kc * 512);
            acc = __builtin_amdgcn_mfma_f32_16x16x32_bf16(A1v, B1v, acc, 0, 0, 0);
            acc = __builtin_amdgcn_mfma_f32_16x16x32_bf16(A1v, B2v, acc, 0, 0, 0);
            acc = __builtin_amdgcn_mfma_f32_16x16x32_bf16(A2v, B1v, acc, 0, 0, 0);
            acc = __builtin_amdgcn_mfma_f32_16x16x32_bf16(A2v, B2v, acc, 0, 0, 0);
            acc = __builtin_amdgcn_mfma_f32_16x16x32_bf16(A1v, B3v, acc, 0, 0, 0);
            acc = __builtin_amdgcn_mfma_f32_16x16x32_bf16(A3v, B1v, acc, 0, 0, 0);
        }
#pragma unroll
        for (int r = 0; r < 4; ++r)
            glds[mt * 16 + (lane >> 4) * 4 + r][nt * 16 + cidx] = acc[r];
        __syncthreads();
        const float* xwp = XW + ((size_t)t * B_ + b) * G4_;
        const float s_i = glds[b][nl]      + xwp[0 * 512 + n];
        const float s_f = glds[b][8 + nl]  + xwp[1 * 512 + n];
        const float s_g = glds[b][16 + nl] + xwp[2 * 512 + n];
        const float s_o = glds[b][24 + nl] + xwp[3 * 512 + n];
        const float ig = 1.f / (1.f + expf(-s_i));
        const float fg = 1.f / (1.f + expf(-s_f));
        const float gg = tanhf(s_g);
        const float og = 1.f / (1.f + expf(-s_o));
        c_reg = fg * c_reg + ig * gg;
        hn = og * tanhf(c_reg);
        write_frags(t + 1, hn);
        asm volatile("s_waitcnt vmcnt(0)" ::: "memory");
        __syncthreads();
        if (tid == 0)
            __hip_atomic_store(&flags[g * 32], t + 2, __ATOMIC_RELAXED,
                               __HIP_MEMORY_SCOPE_AGENT);
    }
}

// ------- batched logits GEMM: W pinned in registers + A staged in LDS (dbuf) --------
__global__ __launch_bounds__(256, 1) void k_gemm(const int* __restrict__ inputs,
                                                 const us* __restrict__ Ah,
                                                 const us* __restrict__ Al,
                                                 const us* __restrict__ Wph,
                                                 const us* __restrict__ Wpl,
                                                 const float* __restrict__ b_out,
                                                 float* __restrict__ sp) {
    __shared__ us abuf[2][32768];   // [buf][A1: 0..16383 | A2: 16384..32767]
    __shared__ float slds[B_][68];
    const int tid = threadIdx.x;
    const int w = tid >> 6, lane = tid & 63;
    const int vt = blockIdx.x * 4 + w;
    const int v0 = blockIdx.x * 64;
    const int c = lane & 15, kg = lane >> 4;
    const int bb = tid >> 3, sub = tid & 7;

    // ---- one-time: W slice -> registers (full unroll + asm pin, R9-validated) ----
    bf8 Bh[16], Bl[16];
#pragma unroll
    for (int kc = 0; kc < 16; ++kc) {
        const size_t wb = (((size_t)vt * 16 + kc) * 64 + lane) * 8;
        Bh[kc] = *reinterpret_cast<const bf8*>(Wph + wb);
        Bl[kc] = *reinterpret_cast<const bf8*>(Wpl + wb);
    }
#pragma unroll
    for (int kc = 0; kc < 16; ++kc)
        asm volatile("" : "+v"(Bh[kc]), "+v"(Bl[kc]));

    // mt-invariant epilogue operands
    float bo[8];
#pragma unroll
    for (int q = 0; q < 8; ++q) bo[q] = b_out[v0 + sub * 8 + q];

    auto stage = [&](int slot, int buf) {   // copy A1[slot]+A2[slot] (64 KB) into abuf[buf]
        const us* s1 = Ah + (size_t)slot * 16384;
        const us* s2 = Al + (size_t)slot * 16384;
        for (int ch = w; ch < 64; ch += 4) {            // 1 KB chunks, identity layout
            const us* src = (ch < 32 ? s1 + ch * 512 : s2 + (ch - 32) * 512) + lane * 8;
            gload_lds16(src, &abuf[buf][ch * 512]);     // wave-uniform LDS base
        }
    };

    stage(1, 0);
    asm volatile("s_waitcnt vmcnt(0)" ::: "memory");
    __builtin_amdgcn_s_barrier();

    for (int mt = 0; mt < S_; ++mt) {
        const int buf = mt & 1;
        if (mt + 1 < S_) stage(mt + 2, buf ^ 1);        // async prefetch into other buffer
        f4 acc0 = {0.f, 0.f, 0.f, 0.f}, acc1 = {0.f, 0.f, 0.f, 0.f};
#pragma unroll
        for (int kc = 0; kc < 16; ++kc) {
            const int o0 = ((kc * 2 + 0) * 64 + lane) * 8;
            const int o1 = ((kc * 2 + 1) * 64 + lane) * 8;
            bf8 A0h = *reinterpret_cast<const bf8*>(&abuf[buf][o0]);
            bf8 A1h = *reinterpret_cast<const bf8*>(&abuf[buf][o1]);
            bf8 A0l = *reinterpret_cast<const bf8*>(&abuf[buf][16384 + o0]);
            bf8 A1l = *reinterpret_cast<const bf8*>(&abuf[buf][16384 + o1]);
            acc0 = __builtin_amdgcn_mfma_f32_16x16x32_bf16(A0h, Bh[kc], acc0, 0, 0, 0);
            acc1 = __builtin_amdgcn_mfma_f32_16x16x32_bf16(A1h, Bh[kc], acc1, 0, 0, 0);
            acc0 = __builtin_amdgcn_mfma_f32_16x16x32_bf16(A0l, Bh[kc], acc0, 0, 0, 0);
            acc1 = __builtin_amdgcn_mfma_f32_16x16x32_bf16(A1l, Bh[kc], acc1, 0, 0, 0);
            acc0 = __builtin_amdgcn_mfma_f32_16x16x32_bf16(A0h, Bl[kc], acc0, 0, 0, 0);
            acc1 = __builtin_amdgcn_mfma_f32_16x16x32_bf16(A1h, Bl[kc], acc1, 0, 0, 0);
        }
        __builtin_amdgcn_s_barrier();                   // prev epilogue's slds reads done
#pragma unroll
        for (int r = 0; r < 4; ++r) {
            slds[kg * 4 + r][w * 16 + c] = acc0[r];
            slds[16 + kg * 4 + r][w * 16 + c] = acc1[r];
        }
        asm volatile("s_waitcnt lgkmcnt(0)" ::: "memory");
        __builtin_amdgcn_s_barrier();
        const int tok = inputs[bb * S_ + mt];
        float m = -INFINITY, s = 0.f, mv = -INFINITY, tv = -INFINITY;
        int mi = 0x7fffffff;
#pragma unroll
        for (int q = 0; q < 8; ++q) {
            const int vl = sub * 8 + q, v = v0 + vl;
            float x = slds[bb][vl] + bo[q];
            float nm = fmaxf(m, x);
            s = s * __expf(m - nm) + __expf(x - nm);
            m = nm;
            if (x > mv) { mv = x; mi = v; }
            if (v == tok) tv = x;
        }
#pragma unroll
        for (int off = 1; off < 8; off <<= 1) {
            float cm = __shfl_xor(m, off), cs = __shfl_xor(s, off);
            float cmv = __shfl_xor(mv, off), ctv = __shfl_xor(tv, off);
            int cmi = __shfl_xor(mi, off);
            float nm = fmaxf(m, cm);
            s = s * __expf(m - nm) + cs * __expf(cm - nm);
            m = nm;
            if (cmv > mv || (cmv == mv && cmi < mi)) { mv = cmv; mi = cmi; }
            tv = fmaxf(tv, ctv);
        }
        if (sub == 0) {
            float* o = sp + ((size_t)(mt * 32 + bb) * NGB + blockIdx.x) * 5;
            o[0] = m; o[1] = s; o[2] = mv; o[3] = (float)mi; o[4] = tv;
        }
        asm volatile("s_waitcnt vmcnt(0)" ::: "memory");   // this wave's stage loads done
        __builtin_amdgcn_s_barrier();                      // all waves' chunks in LDS
    }
}

// ---------------- merge 500 tile-partials per row -> symbols + per-row logp ---------
__global__ __launch_bounds__(256) void k_merge(const float* __restrict__ sp,
                                               float* __restrict__ out,
                                               float* __restrict__ lossbuf) {
    const int tid = threadIdx.x;
    const int mi16 = tid >> 4, l16 = tid & 15;
    const int m = blockIdx.x * 16 + mi16;
    float mm = -INFINITY, s = 0.f, mv = -INFINITY, tv = -INFINITY;
    int ai = 0x7fffffff;
    for (int i = l16; i < NGB; i += 16) {
        const float* o = sp + ((size_t)m * NGB + i) * 5;
        float cm = o[0], cs = o[1], cmv = o[2], ctv = o[4];
        int cmi = (int)o[3];
        float nm = fmaxf(mm, cm);
        s = s * expf(mm - nm) + cs * expf(cm - nm);
        mm = nm;
        if (cmv > mv || (cmv == mv && cmi < ai)) { mv = cmv; ai = cmi; }
        tv = fmaxf(tv, ctv);
    }
#pragma unroll
    for (int off = 1; off < 16; off <<= 1) {
        float cm = __shfl_xor(mm, off), cs = __shfl_xor(s, off);
        float cmv = __shfl_xor(mv, off), ctv = __shfl_xor(tv, off);
        int cmi = __shfl_xor(ai, off);
        float nm = fmaxf(mm, cm);
        s = s * expf(mm - nm) + cs * expf(cm - nm);
        mm = nm;
        if (cmv > mv || (cmv == mv && cmi < ai)) { mv = cmv; ai = cmi; }
        tv = fmaxf(tv, ctv);
    }
    if (l16 == 0) {
        const float logZ = mm + logf(s);
        const int t = m >> 5, b = m & 31;
        out[1 + b * S_ + t] = (float)ai;
        lossbuf[m] = tv - logZ;
    }
}

// ---------------- final: deterministic sum of per-row losses ----------------
__global__ __launch_bounds__(256) void k_sum(const float* __restrict__ lossbuf,
                                             float* __restrict__ out) {
    const int tid = threadIdx.x;
    float a = 0.f;
    for (int i = tid; i < B_ * S_; i += 256) a += lossbuf[i];
    __shared__ float red[256];
    red[tid] = a;
    __syncthreads();
    for (int off = 128; off > 0; off >>= 1) {
        if (tid < off) red[tid] += red[tid + off];
        __syncthreads();
    }
    if (tid == 0) out[0] = -red[0] / (float)B_;
}

extern "C" void kernel_launch(void* const* d_in, const int* in_sizes, int n_in,
                              void* d_out, int out_size, void* d_ws, size_t ws_size,
                              hipStream_t stream) {
    const int*   inputs = (const int*)d_in[0];
    const float* h0     = (const float*)d_in[3];
    const float* c0     = (const float*)d_in[4];
    const float* emb    = (const float*)d_in[5];
    const float* W_ih   = (const float*)d_in[6];
    const float* W_hh   = (const float*)d_in[7];
    const float* b_ih   = (const float*)d_in[8];
    const float* b_hh   = (const float*)d_in[9];
    const float* W_out  = (const float*)d_in[10];
    const float* b_out  = (const float*)d_in[11];
    float* out = (float*)d_out;

    char* p = (char*)d_ws;
    auto alloc = [&](size_t bytes) { char* r = p; p += (bytes + 255) & ~255ull; return r; };
    float* lossbuf  = (float*)alloc((size_t)B_ * S_ * 4);
    int*   flags    = (int*)alloc(64 * 32 * 4);
    float* sp       = (float*)alloc((size_t)B_ * S_ * NGB * 5 * 4);          // 41 MB
    us* A1  = (us*)alloc((size_t)(S_ + 1) * 16384 * 2);
    us* A2  = (us*)alloc((size_t)(S_ + 1) * 16384 * 2);
    us* A3  = (us*)alloc((size_t)(S_ + 1) * 16384 * 2);
    us* Wph = (us*)alloc((size_t)NVT * 16 * 64 * 8 * 2);                     // 32.8 MB
    us* Wpl = (us*)alloc((size_t)NVT * 16 * 64 * 8 * 2);
    us* B1f = (us*)alloc((size_t)RBLK * 16384 * 2);                          // 2.1 MB
    us* B2f = (us*)alloc((size_t)RBLK * 16384 * 2);
    us* B3f = (us*)alloc((size_t)RBLK * 16384 * 2);
    float* XW = (float*)alloc((size_t)S_ * B_ * G4_ * 4);                    // 33.5 MB

    (void)hipMemsetAsync(flags, 0, 64 * 32 * 4, stream);
    k_wsplit<<<(NVT * 16 * 64) / 256, 256, 0, stream>>>(W_out, Wph, Wpl);
    k_whh3<<<(RBLK * 2 * 16 * 64) / 256, 256, 0, stream>>>(W_hh, B1f, B2f, B3f);
    k_xw<<<dim3(8, S_), 256, 0, stream>>>(inputs, emb, W_ih, b_ih, b_hh, XW);
    k_recur<<<RBLK, 256, 0, stream>>>(h0, c0, B1f, B2f, B3f, XW, A1, A2, A3, flags);
    k_gemm<<<NGB, 256, 0, stream>>>(inputs, A1, A2, Wph, Wpl, b_out, sp);
    k_merge<<<(B_ * S_) / 16, 256, 0, stream>>>(sp, out, lossbuf);
    k_sum<<<1, 256, 0, stream>>>(lossbuf, out);
}

// Round 14
// 1728.176 us; speedup vs baseline: 1.4453x; 1.0951x over previous
//
#include <hip/hip_runtime.h>
#include <math.h>

#define B_ 32
#define S_ 128
#define H_ 512
#define V_ 32000
#define G4_ 2048
#define NVT 2000        // W_out 16-col v-tiles
#define NGB 250         // gemm blocks (128 cols each, 8 waves x 16 cols)
#define RBLK 64         // recurrence blocks (n-chunks of 8)

typedef __attribute__((ext_vector_type(8))) short bf8;   // 8 x bf16 fragment
typedef __attribute__((ext_vector_type(4))) float f4;    // MFMA accumulator
typedef unsigned short us;

__device__ __forceinline__ us f2bf(float x) {
    union { float f; unsigned u; } v; v.f = x;
    unsigned r = v.u + 0x7FFFu + ((v.u >> 16) & 1u);     // RNE
    return (us)(r >> 16);
}
__device__ __forceinline__ float bf2f(us b) {
    union { unsigned u; float f; } v; v.u = ((unsigned)b) << 16; return v.f;
}
__device__ __forceinline__ float4 ldf4(const float* p) {
    return *reinterpret_cast<const float4*>(p);
}
__device__ __forceinline__ void gload_lds16(const void* g, void* l) {
    __builtin_amdgcn_global_load_lds((const __attribute__((address_space(1))) unsigned*)g,
                                     (__attribute__((address_space(3))) unsigned*)l, 16, 0, 0);
}

// ------ split W_out into bf16 hi/lo, pre-swizzled to MFMA B-fragment order (once) ----
__global__ __launch_bounds__(256) void k_wsplit(const float* __restrict__ W,
                                                us* __restrict__ Wph,
                                                us* __restrict__ Wpl) {
    const size_t id = (size_t)blockIdx.x * 256 + threadIdx.x;   // 0 .. NVT*16*64-1
    const int lane = (int)(id & 63);
    const size_t fc = id >> 6;            // vt*16 + kc
    const int kc = (int)(fc & 15);
    const size_t vt = fc >> 4;
    const size_t r = vt * 16 + (lane & 15);
    const int k0 = kc * 32 + (lane >> 4) * 8;
    const float* src = W + r * H_ + k0;
    bf8 hv, lv;
#pragma unroll
    for (int e = 0; e < 8; ++e) {
        float x = src[e];
        us hb = f2bf(x);
        hv[e] = (short)hb;
        lv[e] = (short)f2bf(x - bf2f(hb));
    }
    *reinterpret_cast<bf8*>(Wph + id * 8) = hv;
    *reinterpret_cast<bf8*>(Wpl + id * 8) = lv;
}

// ------ split W_hh into THREE bf16 levels, B-fragment order grouped per recur block ---
__global__ __launch_bounds__(256) void k_whh3(const float* __restrict__ W,
                                              us* __restrict__ B1,
                                              us* __restrict__ B2,
                                              us* __restrict__ B3) {
    const size_t id = (size_t)blockIdx.x * 256 + threadIdx.x;  // ((g*2+nt)*16+kc)*64+lane
    const int lane = (int)(id & 63);
    const size_t fc = id >> 6;
    const int kc = (int)(fc & 15);
    const size_t gt = fc >> 4;
    const int nt = (int)(gt & 1);
    const int g = (int)(gt >> 1);
    const int c = lane & 15;
    const int q = nt * 2 + (c >> 3), nl = c & 7;
    const int row = q * 512 + g * 8 + nl;
    const int k0 = kc * 32 + (lane >> 4) * 8;
    const float* src = W + (size_t)row * H_ + k0;
    bf8 v1, v2, v3;
#pragma unroll
    for (int e = 0; e < 8; ++e) {
        float x = src[e];
        us a1 = f2bf(x);
        float r1 = x - bf2f(a1);
        us a2 = f2bf(r1);
        float r2 = r1 - bf2f(a2);
        v1[e] = (short)a1; v2[e] = (short)a2; v3[e] = (short)f2bf(r2);
    }
    *reinterpret_cast<bf8*>(B1 + id * 8) = v1;
    *reinterpret_cast<bf8*>(B2 + id * 8) = v2;
    *reinterpret_cast<bf8*>(B3 + id * 8) = v3;
}

// ------- precompute XW[t][b][j] = emb[tok[b,t]] @ W_ih^T + b_ih + b_hh (once) -------
__global__ __launch_bounds__(256) void k_xw(const int* __restrict__ inputs,
                                            const float* __restrict__ emb,
                                            const float* __restrict__ W_ih,
                                            const float* __restrict__ b_ih,
                                            const float* __restrict__ b_hh,
                                            float* __restrict__ XW) {
    __shared__ float es[16 * H_];
    const int tid = threadIdx.x;
    const int j = blockIdx.x * 256 + tid;
    const int t = blockIdx.y;
    const float bias = b_ih[j] + b_hh[j];
#pragma unroll
    for (int half = 0; half < 2; ++half) {
        __syncthreads();
        for (int idx = tid; idx < 16 * 128; idx += 256) {
            int b = idx >> 7, k4 = (idx & 127) << 2;
            int tok = inputs[(half * 16 + b) * S_ + t];
            *reinterpret_cast<float4*>(&es[b * H_ + k4]) = ldf4(emb + (size_t)tok * H_ + k4);
        }
        __syncthreads();
        float acc[16];
#pragma unroll
        for (int b = 0; b < 16; ++b) acc[b] = 0.f;
        for (int k = 0; k < H_; k += 4) {
            float4 wv = ldf4(W_ih + (size_t)j * H_ + k);
#pragma unroll
            for (int b = 0; b < 16; ++b) {
                float4 xv = *reinterpret_cast<const float4*>(&es[b * H_ + k]);
                acc[b] += wv.x * xv.x + wv.y * xv.y + wv.z * xv.z + wv.w * xv.w;
            }
        }
#pragma unroll
        for (int b = 0; b < 16; ++b)
            XW[(size_t)(t * B_ + half * 16 + b) * G4_ + j] = acc[b] + bias;
    }
}

// ------- the MFMA recurrence: 64 blocks, fence-free flag sync, 3-acc chain split -----
__global__ __launch_bounds__(256)
void k_recur(const float* __restrict__ h0, const float* __restrict__ c0,
             const us* __restrict__ B1f, const us* __restrict__ B2f,
             const us* __restrict__ B3f, const float* __restrict__ XW,
             us* __restrict__ A1, us* __restrict__ A2,
             us* __restrict__ A3, int* __restrict__ flags) {
    __shared__ us wl1[16384], wl2[16384], wl3[16384];   // 3 x 32 KB
    __shared__ float glds[32][33];                      // gates exchange
    const int g = blockIdx.x, tid = threadIdx.x;

    // load this block's W_hh fragments into LDS (once)
    {
        const size_t base = (size_t)g * 16384;
        for (int i = tid; i < 2048; i += 256) {
            reinterpret_cast<uint4*>(wl1)[i] = reinterpret_cast<const uint4*>(B1f + base)[i];
            reinterpret_cast<uint4*>(wl2)[i] = reinterpret_cast<const uint4*>(B2f + base)[i];
            reinterpret_cast<uint4*>(wl3)[i] = reinterpret_cast<const uint4*>(B3f + base)[i];
        }
    }
    // cell-thread identity: (b, nl); n = g*8+nl owned forever (c stays in a register)
    const int b = tid >> 3, nl = tid & 7;
    const int n = g * 8 + nl;
    const int kc_w = g >> 2, kg_w = g & 3, half_w = b >> 4, lane_w = kg_w * 16 + (b & 15);
    float c_reg = c0[b * H_ + n];
    float hn = h0[b * H_ + n];

    auto write_frags = [&](int slot, float h) {
        us a1 = f2bf(h);
        float r1 = h - bf2f(a1);
        us a2 = f2bf(r1);
        us a3 = f2bf(r1 - bf2f(a2));
        unsigned v1 = a1, v2 = a2, v3 = a3;
        unsigned q1 = (unsigned)__shfl_xor((int)v1, 1);
        unsigned q2 = (unsigned)__shfl_xor((int)v2, 1);
        unsigned q3 = (unsigned)__shfl_xor((int)v3, 1);
        if ((nl & 1) == 0) {
            const size_t ix = ((((size_t)slot * 16 + kc_w) * 2 + half_w) * 64 + lane_w) * 8 + nl;
            __hip_atomic_store((unsigned*)(A1 + ix), v1 | (q1 << 16),
                               __ATOMIC_RELAXED, __HIP_MEMORY_SCOPE_AGENT);
            __hip_atomic_store((unsigned*)(A2 + ix), v2 | (q2 << 16),
                               __ATOMIC_RELAXED, __HIP_MEMORY_SCOPE_AGENT);
            __hip_atomic_store((unsigned*)(A3 + ix), v3 | (q3 << 16),
                               __ATOMIC_RELAXED, __HIP_MEMORY_SCOPE_AGENT);
        }
    };
    write_frags(0, hn);          // slot 0 = h_{-1} = h0
    asm volatile("s_waitcnt vmcnt(0)" ::: "memory");   // stores acked at L3
    __syncthreads();
    if (tid == 0)
        __hip_atomic_store(&flags[g * 32], 1, __ATOMIC_RELAXED, __HIP_MEMORY_SCOPE_AGENT);

    // wave roles for the MFMA phase
    const int wv = tid >> 6, lane = tid & 63;
    const int mt = wv >> 1, nt = wv & 1;
    const int cidx = lane & 15;

    for (int t = 0; t < S_; ++t) {
        // prefetch XW[t] (h-independent) before the poll
        const float* xwp = XW + ((size_t)t * B_ + b) * G4_;
        float xw0 = xwp[n], xw1 = xwp[512 + n], xw2 = xwp[1024 + n], xw3 = xwp[1536 + n];
        if (tid < 64) {
            int spins = 0;
            while (__hip_atomic_load(&flags[tid * 32], __ATOMIC_RELAXED,
                                     __HIP_MEMORY_SCOPE_AGENT) < t + 1) {
                __builtin_amdgcn_s_sleep(1);
                if (++spins > (1 << 18)) break;
            }
        }
        __syncthreads();
        // 6-term MFMA, 3 accumulators (break serial dependency chain)
        f4 aA = {0.f, 0.f, 0.f, 0.f}, aB = {0.f, 0.f, 0.f, 0.f}, aC = {0.f, 0.f, 0.f, 0.f};
        const us* a1p = A1 + ((((size_t)t * 16) * 2 + mt) * 64 + lane) * 8;
        const us* a2p = A2 + ((((size_t)t * 16) * 2 + mt) * 64 + lane) * 8;
        const us* a3p = A3 + ((((size_t)t * 16) * 2 + mt) * 64 + lane) * 8;
        const us* b1p = wl1 + ((size_t)(nt * 16) * 64 + lane) * 8;
        const us* b2p = wl2 + ((size_t)(nt * 16) * 64 + lane) * 8;
        const us* b3p = wl3 + ((size_t)(nt * 16) * 64 + lane) * 8;
#pragma unroll 4
        for (int kc = 0; kc < 16; ++kc) {
            bf8 A1v = *reinterpret_cast<const bf8*>(a1p + (size_t)kc * 1024);
            bf8 A2v = *reinterpret_cast<const bf8*>(a2p + (size_t)kc * 1024);
            bf8 A3v = *reinterpret_cast<const bf8*>(a3p + (size_t)kc * 1024);
            bf8 B1v = *reinterpret_cast<const bf8*>(b1p + (size_t)kc * 512);
            bf8 B2v = *reinterpret_cast<const bf8*>(b2p + (size_t)kc * 512);
            bf8 B3v = *reinterpret_cast<const bf8*>(b3p + (size_t)kc * 512);
            aA = __builtin_amdgcn_mfma_f32_16x16x32_bf16(A1v, B1v, aA, 0, 0, 0);
            aB = __builtin_amdgcn_mfma_f32_16x16x32_bf16(A1v, B2v, aB, 0, 0, 0);
            aA = __builtin_amdgcn_mfma_f32_16x16x32_bf16(A2v, B1v, aA, 0, 0, 0);
            aB = __builtin_amdgcn_mfma_f32_16x16x32_bf16(A2v, B2v, aB, 0, 0, 0);
            aC = __builtin_amdgcn_mfma_f32_16x16x32_bf16(A1v, B3v, aC, 0, 0, 0);
            aC = __builtin_amdgcn_mfma_f32_16x16x32_bf16(A3v, B1v, aC, 0, 0, 0);
        }
        f4 acc = aA + aB;
        acc = acc + aC;
#pragma unroll
        for (int r = 0; r < 4; ++r)
            glds[mt * 16 + (lane >> 4) * 4 + r][nt * 16 + cidx] = acc[r];
        __syncthreads();
        const float s_i = glds[b][nl]      + xw0;
        const float s_f = glds[b][8 + nl]  + xw1;
        const float s_g = glds[b][16 + nl] + xw2;
        const float s_o = glds[b][24 + nl] + xw3;
        const float ig = 1.f / (1.f + expf(-s_i));
        const float fg = 1.f / (1.f + expf(-s_f));
        const float gg = tanhf(s_g);
        const float og = 1.f / (1.f + expf(-s_o));
        c_reg = fg * c_reg + ig * gg;
        hn = og * tanhf(c_reg);
        write_frags(t + 1, hn);
        asm volatile("s_waitcnt vmcnt(0)" ::: "memory");
        __syncthreads();
        if (tid == 0)
            __hip_atomic_store(&flags[g * 32], t + 2, __ATOMIC_RELAXED,
                               __HIP_MEMORY_SCOPE_AGENT);
    }
}

// -- batched logits GEMM: 250 blocks x 8 waves, W pinned, A staged in LDS (dbuf) -----
__global__ __launch_bounds__(512, 1) void k_gemm(const int* __restrict__ inputs,
                                                 const us* __restrict__ Ah,
                                                 const us* __restrict__ Al,
                                                 const us* __restrict__ Wph,
                                                 const us* __restrict__ Wpl,
                                                 const float* __restrict__ b_out,
                                                 float* __restrict__ sp) {
    __shared__ us abuf[2][32768];   // [buf][A1: 0..16383 | A2: 16384..32767]  128 KB
    __shared__ float slds[B_][132]; // 32 rows x 128 cols (+pad)               16.9 KB
    const int tid = threadIdx.x;
    const int w = tid >> 6, lane = tid & 63;
    const int vt = blockIdx.x * 8 + w;
    const int v0 = blockIdx.x * 128;
    const int c = lane & 15, kg = lane >> 4;
    const int bb = tid >> 4, sub = tid & 15;

    // ---- one-time: W slice -> registers (full unroll + asm pin, R9-validated) ----
    bf8 Bh[16], Bl[16];
#pragma unroll
    for (int kc = 0; kc < 16; ++kc) {
        const size_t wb = (((size_t)vt * 16 + kc) * 64 + lane) * 8;
        Bh[kc] = *reinterpret_cast<const bf8*>(Wph + wb);
        Bl[kc] = *reinterpret_cast<const bf8*>(Wpl + wb);
    }
#pragma unroll
    for (int kc = 0; kc < 16; ++kc)
        asm volatile("" : "+v"(Bh[kc]), "+v"(Bl[kc]));

    // mt-invariant epilogue operands (8 cols per thread)
    float bo[8];
#pragma unroll
    for (int q = 0; q < 8; ++q) bo[q] = b_out[v0 + sub * 8 + q];

    auto stage = [&](int slot, int buf) {   // copy A1[slot]+A2[slot] (64 KB) into abuf[buf]
        const us* s1 = Ah + (size_t)slot * 16384;
        const us* s2 = Al + (size_t)slot * 16384;
        for (int ch = w; ch < 64; ch += 8) {            // 1 KB chunks, identity layout
            const us* src = (ch < 32 ? s1 + ch * 512 : s2 + (ch - 32) * 512) + lane * 8;
            gload_lds16(src, &abuf[buf][ch * 512]);     // wave-uniform LDS base
        }
    };

    stage(1, 0);
    asm volatile("s_waitcnt vmcnt(0)" ::: "memory");
    __builtin_amdgcn_s_barrier();

    for (int mt = 0; mt < S_; ++mt) {
        const int buf = mt & 1;
        if (mt + 1 < S_) stage(mt + 2, buf ^ 1);        // async prefetch into other buffer
        f4 acc0 = {0.f, 0.f, 0.f, 0.f}, acc1 = {0.f, 0.f, 0.f, 0.f};
#pragma unroll
        for (int kc = 0; kc < 16; ++kc) {
            const int o0 = ((kc * 2 + 0) * 64 + lane) * 8;
            const int o1 = ((kc * 2 + 1) * 64 + lane) * 8;
            bf8 A0h = *reinterpret_cast<const bf8*>(&abuf[buf][o0]);
            bf8 A1h = *reinterpret_cast<const bf8*>(&abuf[buf][o1]);
            bf8 A0l = *reinterpret_cast<const bf8*>(&abuf[buf][16384 + o0]);
            bf8 A1l = *reinterpret_cast<const bf8*>(&abuf[buf][16384 + o1]);
            acc0 = __builtin_amdgcn_mfma_f32_16x16x32_bf16(A0h, Bh[kc], acc0, 0, 0, 0);
            acc1 = __builtin_amdgcn_mfma_f32_16x16x32_bf16(A1h, Bh[kc], acc1, 0, 0, 0);
            acc0 = __builtin_amdgcn_mfma_f32_16x16x32_bf16(A0l, Bh[kc], acc0, 0, 0, 0);
            acc1 = __builtin_amdgcn_mfma_f32_16x16x32_bf16(A1l, Bh[kc], acc1, 0, 0, 0);
            acc0 = __builtin_amdgcn_mfma_f32_16x16x32_bf16(A0h, Bl[kc], acc0, 0, 0, 0);
            acc1 = __builtin_amdgcn_mfma_f32_16x16x32_bf16(A1h, Bl[kc], acc1, 0, 0, 0);
        }
        __builtin_amdgcn_s_barrier();                   // prev epilogue's slds reads done
#pragma unroll
        for (int r = 0; r < 4; ++r) {
            slds[kg * 4 + r][w * 16 + c] = acc0[r];
            slds[16 + kg * 4 + r][w * 16 + c] = acc1[r];
        }
        asm volatile("s_waitcnt lgkmcnt(0)" ::: "memory");
        __builtin_amdgcn_s_barrier();
        const int tok = inputs[bb * S_ + mt];
        float m = -INFINITY, s = 0.f, mv = -INFINITY, tv = -INFINITY;
        int mi = 0x7fffffff;
#pragma unroll
        for (int q = 0; q < 8; ++q) {
            const int vl = sub * 8 + q, v = v0 + vl;
            float x = slds[bb][vl] + bo[q];
            float nm = fmaxf(m, x);
            s = s * __expf(m - nm) + __expf(x - nm);
            m = nm;
            if (x > mv) { mv = x; mi = v; }
            if (v == tok) tv = x;
        }
#pragma unroll
        for (int off = 1; off < 16; off <<= 1) {
            float cm = __shfl_xor(m, off), cs = __shfl_xor(s, off);
            float cmv = __shfl_xor(mv, off), ctv = __shfl_xor(tv, off);
            int cmi = __shfl_xor(mi, off);
            float nm = fmaxf(m, cm);
            s = s * __expf(m - nm) + cs * __expf(cm - nm);
            m = nm;
            if (cmv > mv || (cmv == mv && cmi < mi)) { mv = cmv; mi = cmi; }
            tv = fmaxf(tv, ctv);
        }
        if (sub == 0) {
            float* o = sp + ((size_t)(mt * 32 + bb) * NGB + blockIdx.x) * 5;
            o[0] = m; o[1] = s; o[2] = mv; o[3] = (float)mi; o[4] = tv;
        }
        asm volatile("s_waitcnt vmcnt(0)" ::: "memory");   // this wave's stage loads done
        __builtin_amdgcn_s_barrier();                      // all waves' chunks in LDS
    }
}

// ---------------- merge 250 tile-partials per row -> symbols + per-row logp ---------
__global__ __launch_bounds__(256) void k_merge(const float* __restrict__ sp,
                                               float* __restrict__ out,
                                               float* __restrict__ lossbuf) {
    const int tid = threadIdx.x;
    const int mi16 = tid >> 4, l16 = tid & 15;
    const int m = blockIdx.x * 16 + mi16;
    float mm = -INFINITY, s = 0.f, mv = -INFINITY, tv = -INFINITY;
    int ai = 0x7fffffff;
    for (int i = l16; i < NGB; i += 16) {
        const float* o = sp + ((size_t)m * NGB + i) * 5;
        float cm = o[0], cs = o[1], cmv = o[2], ctv = o[4];
        int cmi = (int)o[3];
        float nm = fmaxf(mm, cm);
        s = s * expf(mm - nm) + cs * expf(cm - nm);
        mm = nm;
        if (cmv > mv || (cmv == mv && cmi < ai)) { mv = cmv; ai = cmi; }
        tv = fmaxf(tv, ctv);
    }
#pragma unroll
    for (int off = 1; off < 16; off <<= 1) {
        float cm = __shfl_xor(mm, off), cs = __shfl_xor(s, off);
        float cmv = __shfl_xor(mv, off), ctv = __shfl_xor(tv, off);
        int cmi = __shfl_xor(ai, off);
        float nm = fmaxf(mm, cm);
        s = s * expf(mm - nm) + cs * expf(cm - nm);
        mm = nm;
        if (cmv > mv || (cmv == mv && cmi < ai)) { mv = cmv; ai = cmi; }
        tv = fmaxf(tv, ctv);
    }
    if (l16 == 0) {
        const float logZ = mm + logf(s);
        const int t = m >> 5, b = m & 31;
        out[1 + b * S_ + t] = (float)ai;
        lossbuf[m] = tv - logZ;
    }
}

// ---------------- final: deterministic sum of per-row losses ----------------
__global__ __launch_bounds__(256) void k_sum(const float* __restrict__ lossbuf,
                                             float* __restrict__ out) {
    const int tid = threadIdx.x;
    float a = 0.f;
    for (int i = tid; i < B_ * S_; i += 256) a += lossbuf[i];
    __shared__ float red[256];
    red[tid] = a;
    __syncthreads();
    for (int off = 128; off > 0; off >>= 1) {
        if (tid < off) red[tid] += red[tid + off];
        __syncthreads();
    }
    if (tid == 0) out[0] = -red[0] / (float)B_;
}

extern "C" void kernel_launch(void* const* d_in, const int* in_sizes, int n_in,
                              void* d_out, int out_size, void* d_ws, size_t ws_size,
                              hipStream_t stream) {
    const int*   inputs = (const int*)d_in[0];
    const float* h0     = (const float*)d_in[3];
    const float* c0     = (const float*)d_in[4];
    const float* emb    = (const float*)d_in[5];
    const float* W_ih   = (const float*)d_in[6];
    const float* W_hh   = (const float*)d_in[7];
    const float* b_ih   = (const float*)d_in[8];
    const float* b_hh   = (const float*)d_in[9];
    const float* W_out  = (const float*)d_in[10];
    const float* b_out  = (const float*)d_in[11];
    float* out = (float*)d_out;

    char* p = (char*)d_ws;
    auto alloc = [&](size_t bytes) { char* r = p; p += (bytes + 255) & ~255ull; return r; };
    float* lossbuf  = (float*)alloc((size_t)B_ * S_ * 4);
    int*   flags    = (int*)alloc(64 * 32 * 4);
    float* sp       = (float*)alloc((size_t)B_ * S_ * NGB * 5 * 4);          // 20.5 MB
    us* A1  = (us*)alloc((size_t)(S_ + 1) * 16384 * 2);
    us* A2  = (us*)alloc((size_t)(S_ + 1) * 16384 * 2);
    us* A3  = (us*)alloc((size_t)(S_ + 1) * 16384 * 2);
    us* Wph = (us*)alloc((size_t)NVT * 16 * 64 * 8 * 2);                     // 32.8 MB
    us* Wpl = (us*)alloc((size_t)NVT * 16 * 64 * 8 * 2);
    us* B1f = (us*)alloc((size_t)RBLK * 16384 * 2);                          // 2.1 MB
    us* B2f = (us*)alloc((size_t)RBLK * 16384 * 2);
    us* B3f = (us*)alloc((size_t)RBLK * 16384 * 2);
    float* XW = (float*)alloc((size_t)S_ * B_ * G4_ * 4);                    // 33.5 MB

    (void)hipMemsetAsync(flags, 0, 64 * 32 * 4, stream);
    k_wsplit<<<(NVT * 16 * 64) / 256, 256, 0, stream>>>(W_out, Wph, Wpl);
    k_whh3<<<(RBLK * 2 * 16 * 64) / 256, 256, 0, stream>>>(W_hh, B1f, B2f, B3f);
    k_xw<<<dim3(8, S_), 256, 0, stream>>>(inputs, emb, W_ih, b_ih, b_hh, XW);
    k_recur<<<RBLK, 256, 0, stream>>>(h0, c0, B1f, B2f, B3f, XW, A1, A2, A3, flags);
    k_gemm<<<NGB, 512, 0, stream>>>(inputs, A1, A2, Wph, Wpl, b_out, sp);
    k_merge<<<(B_ * S_) / 16, 256, 0, stream>>>(sp, out, lossbuf);
    k_sum<<<1, 256, 0, stream>>>(lossbuf, out);
}

// Round 15
// 1550.558 us; speedup vs baseline: 1.6109x; 1.1146x over previous
//
#include <hip/hip_runtime.h>
#include <math.h>

#define B_ 32
#define S_ 128
#define H_ 512
#define V_ 32000
#define G4_ 2048
#define NGB 250         // gemm blocks (128 cols each, 8 waves x 16 cols)
#define RBLK 64         // recurrence blocks (n-chunks of 8)

typedef __attribute__((ext_vector_type(8))) short bf8;   // 8 x bf16 fragment
typedef __attribute__((ext_vector_type(4))) float f4;    // MFMA accumulator
typedef unsigned short us;

__device__ __forceinline__ us f2bf(float x) {
    union { float f; unsigned u; } v; v.f = x;
    unsigned r = v.u + 0x7FFFu + ((v.u >> 16) & 1u);     // RNE
    return (us)(r >> 16);
}
__device__ __forceinline__ float bf2f(us b) {
    union { unsigned u; float f; } v; v.u = ((unsigned)b) << 16; return v.f;
}
__device__ __forceinline__ float4 ldf4(const float* p) {
    return *reinterpret_cast<const float4*>(p);
}
__device__ __forceinline__ void gload_lds16(const void* g, void* l) {
    __builtin_amdgcn_global_load_lds((const __attribute__((address_space(1))) unsigned*)g,
                                     (__attribute__((address_space(3))) unsigned*)l, 16, 0, 0);
}

// ------ split W_hh into THREE bf16 levels, B-fragment order grouped per recur block ---
__global__ __launch_bounds__(256) void k_whh3(const float* __restrict__ W,
                                              us* __restrict__ B1,
                                              us* __restrict__ B2,
                                              us* __restrict__ B3) {
    const size_t id = (size_t)blockIdx.x * 256 + threadIdx.x;  // ((g*2+nt)*16+kc)*64+lane
    const int lane = (int)(id & 63);
    const size_t fc = id >> 6;
    const int kc = (int)(fc & 15);
    const size_t gt = fc >> 4;
    const int nt = (int)(gt & 1);
    const int g = (int)(gt >> 1);
    const int c = lane & 15;
    const int q = nt * 2 + (c >> 3), nl = c & 7;
    const int row = q * 512 + g * 8 + nl;
    const int k0 = kc * 32 + (lane >> 4) * 8;
    const float* src = W + (size_t)row * H_ + k0;
    bf8 v1, v2, v3;
#pragma unroll
    for (int e = 0; e < 8; ++e) {
        float x = src[e];
        us a1 = f2bf(x);
        float r1 = x - bf2f(a1);
        us a2 = f2bf(r1);
        float r2 = r1 - bf2f(a2);
        v1[e] = (short)a1; v2[e] = (short)a2; v3[e] = (short)f2bf(r2);
    }
    *reinterpret_cast<bf8*>(B1 + id * 8) = v1;
    *reinterpret_cast<bf8*>(B2 + id * 8) = v2;
    *reinterpret_cast<bf8*>(B3 + id * 8) = v3;
}

// ------- precompute XW[t][b][j] = emb[tok[b,t]] @ W_ih^T + b_ih + b_hh (once) -------
__global__ __launch_bounds__(256) void k_xw(const int* __restrict__ inputs,
                                            const float* __restrict__ emb,
                                            const float* __restrict__ W_ih,
                                            const float* __restrict__ b_ih,
                                            const float* __restrict__ b_hh,
                                            float* __restrict__ XW) {
    __shared__ float es[16 * H_];
    const int tid = threadIdx.x;
    const int j = blockIdx.x * 256 + tid;
    const int t = blockIdx.y;
    const float bias = b_ih[j] + b_hh[j];
#pragma unroll
    for (int half = 0; half < 2; ++half) {
        __syncthreads();
        for (int idx = tid; idx < 16 * 128; idx += 256) {
            int b = idx >> 7, k4 = (idx & 127) << 2;
            int tok = inputs[(half * 16 + b) * S_ + t];
            *reinterpret_cast<float4*>(&es[b * H_ + k4]) = ldf4(emb + (size_t)tok * H_ + k4);
        }
        __syncthreads();
        float acc[16];
#pragma unroll
        for (int b = 0; b < 16; ++b) acc[b] = 0.f;
        for (int k = 0; k < H_; k += 4) {
            float4 wv = ldf4(W_ih + (size_t)j * H_ + k);
#pragma unroll
            for (int b = 0; b < 16; ++b) {
                float4 xv = *reinterpret_cast<const float4*>(&es[b * H_ + k]);
                acc[b] += wv.x * xv.x + wv.y * xv.y + wv.z * xv.z + wv.w * xv.w;
            }
        }
#pragma unroll
        for (int b = 0; b < 16; ++b)
            XW[(size_t)(t * B_ + half * 16 + b) * G4_ + j] = acc[b] + bias;
    }
}

// ---------------- the MFMA recurrence: 64 blocks, fence-free flag sync (R9/R13) ------
__global__ __launch_bounds__(256)
void k_recur(const float* __restrict__ h0, const float* __restrict__ c0,
             const us* __restrict__ B1f, const us* __restrict__ B2f,
             const us* __restrict__ B3f, const float* __restrict__ XW,
             us* __restrict__ A1, us* __restrict__ A2,
             us* __restrict__ A3, int* __restrict__ flags) {
    __shared__ us wl1[16384], wl2[16384], wl3[16384];   // 3 x 32 KB
    __shared__ float glds[32][33];                      // gates exchange
    const int g = blockIdx.x, tid = threadIdx.x;

    // load this block's W_hh fragments into LDS (once)
    {
        const size_t base = (size_t)g * 16384;
        for (int i = tid; i < 2048; i += 256) {
            reinterpret_cast<uint4*>(wl1)[i] = reinterpret_cast<const uint4*>(B1f + base)[i];
            reinterpret_cast<uint4*>(wl2)[i] = reinterpret_cast<const uint4*>(B2f + base)[i];
            reinterpret_cast<uint4*>(wl3)[i] = reinterpret_cast<const uint4*>(B3f + base)[i];
        }
    }
    // cell-thread identity: (b, nl); n = g*8+nl owned forever (c stays in a register)
    const int b = tid >> 3, nl = tid & 7;
    const int n = g * 8 + nl;
    const int kc_w = g >> 2, kg_w = g & 3, half_w = b >> 4, lane_w = kg_w * 16 + (b & 15);
    float c_reg = c0[b * H_ + n];
    float hn = h0[b * H_ + n];

    auto write_frags = [&](int slot, float h) {
        us a1 = f2bf(h);
        float r1 = h - bf2f(a1);
        us a2 = f2bf(r1);
        us a3 = f2bf(r1 - bf2f(a2));
        unsigned v1 = a1, v2 = a2, v3 = a3;
        unsigned q1 = (unsigned)__shfl_xor((int)v1, 1);
        unsigned q2 = (unsigned)__shfl_xor((int)v2, 1);
        unsigned q3 = (unsigned)__shfl_xor((int)v3, 1);
        if ((nl & 1) == 0) {
            const size_t ix = ((((size_t)slot * 16 + kc_w) * 2 + half_w) * 64 + lane_w) * 8 + nl;
            __hip_atomic_store((unsigned*)(A1 + ix), v1 | (q1 << 16),
                               __ATOMIC_RELAXED, __HIP_MEMORY_SCOPE_AGENT);
            __hip_atomic_store((unsigned*)(A2 + ix), v2 | (q2 << 16),
                               __ATOMIC_RELAXED, __HIP_MEMORY_SCOPE_AGENT);
            __hip_atomic_store((unsigned*)(A3 + ix), v3 | (q3 << 16),
                               __ATOMIC_RELAXED, __HIP_MEMORY_SCOPE_AGENT);
        }
    };
    write_frags(0, hn);          // slot 0 = h_{-1} = h0
    asm volatile("s_waitcnt vmcnt(0)" ::: "memory");   // stores acked at L3
    __syncthreads();
    if (tid == 0)
        __hip_atomic_store(&flags[g * 32], 1, __ATOMIC_RELAXED, __HIP_MEMORY_SCOPE_AGENT);

    // wave roles for the MFMA phase
    const int wv = tid >> 6, lane = tid & 63;
    const int mt = wv >> 1, nt = wv & 1;
    const int cidx = lane & 15;

    for (int t = 0; t < S_; ++t) {
        if (tid < 64) {
            int spins = 0;
            while (__hip_atomic_load(&flags[tid * 32], __ATOMIC_RELAXED,
                                     __HIP_MEMORY_SCOPE_AGENT) < t + 1) {
                __builtin_amdgcn_s_sleep(1);
                if (++spins > (1 << 18)) break;
            }
        }
        __syncthreads();
        f4 acc = {0.f, 0.f, 0.f, 0.f};
        const us* a1p = A1 + ((((size_t)t * 16) * 2 + mt) * 64 + lane) * 8;
        const us* a2p = A2 + ((((size_t)t * 16) * 2 + mt) * 64 + lane) * 8;
        const us* a3p = A3 + ((((size_t)t * 16) * 2 + mt) * 64 + lane) * 8;
        const us* b1p = wl1 + ((size_t)(nt * 16) * 64 + lane) * 8;
        const us* b2p = wl2 + ((size_t)(nt * 16) * 64 + lane) * 8;
        const us* b3p = wl3 + ((size_t)(nt * 16) * 64 + lane) * 8;
#pragma unroll 4
        for (int kc = 0; kc < 16; ++kc) {
            bf8 A1v = *reinterpret_cast<const bf8*>(a1p + (size_t)kc * 1024);
            bf8 A2v = *reinterpret_cast<const bf8*>(a2p + (size_t)kc * 1024);
            bf8 A3v = *reinterpret_cast<const bf8*>(a3p + (size_t)kc * 1024);
            bf8 B1v = *reinterpret_cast<const bf8*>(b1p + (size_t)kc * 512);
            bf8 B2v = *reinterpret_cast<const bf8*>(b2p + (size_t)kc * 512);
            bf8 B3v = *reinterpret_cast<const bf8*>(b3p + (size_t)kc * 512);
            acc = __builtin_amdgcn_mfma_f32_16x16x32_bf16(A1v, B1v, acc, 0, 0, 0);
            acc = __builtin_amdgcn_mfma_f32_16x16x32_bf16(A1v, B2v, acc, 0, 0, 0);
            acc = __builtin_amdgcn_mfma_f32_16x16x32_bf16(A2v, B1v, acc, 0, 0, 0);
            acc = __builtin_amdgcn_mfma_f32_16x16x32_bf16(A2v, B2v, acc, 0, 0, 0);
            acc = __builtin_amdgcn_mfma_f32_16x16x32_bf16(A1v, B3v, acc, 0, 0, 0);
            acc = __builtin_amdgcn_mfma_f32_16x16x32_bf16(A3v, B1v, acc, 0, 0, 0);
        }
#pragma unroll
        for (int r = 0; r < 4; ++r)
            glds[mt * 16 + (lane >> 4) * 4 + r][nt * 16 + cidx] = acc[r];
        __syncthreads();
        const float* xwp = XW + ((size_t)t * B_ + b) * G4_;
        const float s_i = glds[b][nl]      + xwp[0 * 512 + n];
        const float s_f = glds[b][8 + nl]  + xwp[1 * 512 + n];
        const float s_g = glds[b][16 + nl] + xwp[2 * 512 + n];
        const float s_o = glds[b][24 + nl] + xwp[3 * 512 + n];
        const float ig = 1.f / (1.f + expf(-s_i));
        const float fg = 1.f / (1.f + expf(-s_f));
        const float gg = tanhf(s_g);
        const float og = 1.f / (1.f + expf(-s_o));
        c_reg = fg * c_reg + ig * gg;
        hn = og * tanhf(c_reg);
        write_frags(t + 1, hn);
        asm volatile("s_waitcnt vmcnt(0)" ::: "memory");
        __syncthreads();
        if (tid == 0)
            __hip_atomic_store(&flags[g * 32], t + 2, __ATOMIC_RELAXED,
                               __HIP_MEMORY_SCOPE_AGENT);
    }
}

// -- batched logits GEMM: 250 blocks x 8 waves; W split fp32->bf16 in-kernel, pinned --
__global__ __launch_bounds__(512, 1) void k_gemm(const int* __restrict__ inputs,
                                                 const us* __restrict__ Ah,
                                                 const us* __restrict__ Al,
                                                 const float* __restrict__ Wout,
                                                 const float* __restrict__ b_out,
                                                 float* __restrict__ sp) {
    __shared__ us abuf[2][32768];   // [buf][A1: 0..16383 | A2: 16384..32767]  128 KB
    __shared__ float slds[B_][132]; // 32 rows x 128 cols (+pad)               16.9 KB
    const int tid = threadIdx.x;
    const int w = tid >> 6, lane = tid & 63;
    const int vt = blockIdx.x * 8 + w;
    const int v0 = blockIdx.x * 128;
    const int c = lane & 15, kg = lane >> 4;
    const int bb = tid >> 4, sub = tid & 15;

    // ---- one-time: read fp32 W slice, split to bf16 hi/lo fragments, pin in regs ----
    // layout identical to the old k_wsplit: row = vt*16 + (lane&15), k = kc*32 + (lane>>4)*8
    bf8 Bh[16], Bl[16];
    {
        const float* wrow = Wout + (size_t)(vt * 16 + c) * H_ + kg * 8;
#pragma unroll
        for (int kc = 0; kc < 16; ++kc) {
            const float* src = wrow + kc * 32;
            float4 w0 = ldf4(src), w1 = ldf4(src + 4);
            bf8 hv, lv;
            float xs[8] = {w0.x, w0.y, w0.z, w0.w, w1.x, w1.y, w1.z, w1.w};
#pragma unroll
            for (int e = 0; e < 8; ++e) {
                us hb = f2bf(xs[e]);
                hv[e] = (short)hb;
                lv[e] = (short)f2bf(xs[e] - bf2f(hb));
            }
            Bh[kc] = hv;
            Bl[kc] = lv;
        }
    }
#pragma unroll
    for (int kc = 0; kc < 16; ++kc)
        asm volatile("" : "+v"(Bh[kc]), "+v"(Bl[kc]));

    // mt-invariant epilogue operands (8 cols per thread)
    float bo[8];
#pragma unroll
    for (int q = 0; q < 8; ++q) bo[q] = b_out[v0 + sub * 8 + q];

    auto stage = [&](int slot, int buf) {   // copy A1[slot]+A2[slot] (64 KB) into abuf[buf]
        const us* s1 = Ah + (size_t)slot * 16384;
        const us* s2 = Al + (size_t)slot * 16384;
        for (int ch = w; ch < 64; ch += 8) {            // 1 KB chunks, identity layout
            const us* src = (ch < 32 ? s1 + ch * 512 : s2 + (ch - 32) * 512) + lane * 8;
            gload_lds16(src, &abuf[buf][ch * 512]);     // wave-uniform LDS base
        }
    };

    stage(1, 0);
    asm volatile("s_waitcnt vmcnt(0)" ::: "memory");
    __builtin_amdgcn_s_barrier();

    for (int mt = 0; mt < S_; ++mt) {
        const int buf = mt & 1;
        if (mt + 1 < S_) stage(mt + 2, buf ^ 1);        // async prefetch into other buffer
        f4 acc0 = {0.f, 0.f, 0.f, 0.f}, acc1 = {0.f, 0.f, 0.f, 0.f};
#pragma unroll
        for (int kc = 0; kc < 16; ++kc) {
            const int o0 = ((kc * 2 + 0) * 64 + lane) * 8;
            const int o1 = ((kc * 2 + 1) * 64 + lane) * 8;
            bf8 A0h = *reinterpret_cast<const bf8*>(&abuf[buf][o0]);
            bf8 A1h = *reinterpret_cast<const bf8*>(&abuf[buf][o1]);
            bf8 A0l = *reinterpret_cast<const bf8*>(&abuf[buf][16384 + o0]);
            bf8 A1l = *reinterpret_cast<const bf8*>(&abuf[buf][16384 + o1]);
            acc0 = __builtin_amdgcn_mfma_f32_16x16x32_bf16(A0h, Bh[kc], acc0, 0, 0, 0);
            acc1 = __builtin_amdgcn_mfma_f32_16x16x32_bf16(A1h, Bh[kc], acc1, 0, 0, 0);
            acc0 = __builtin_amdgcn_mfma_f32_16x16x32_bf16(A0l, Bh[kc], acc0, 0, 0, 0);
            acc1 = __builtin_amdgcn_mfma_f32_16x16x32_bf16(A1l, Bh[kc], acc1, 0, 0, 0);
            acc0 = __builtin_amdgcn_mfma_f32_16x16x32_bf16(A0h, Bl[kc], acc0, 0, 0, 0);
            acc1 = __builtin_amdgcn_mfma_f32_16x16x32_bf16(A1h, Bl[kc], acc1, 0, 0, 0);
        }
        __builtin_amdgcn_s_barrier();                   // prev epilogue's slds reads done
#pragma unroll
        for (int r = 0; r < 4; ++r) {
            slds[kg * 4 + r][w * 16 + c] = acc0[r];
            slds[16 + kg * 4 + r][w * 16 + c] = acc1[r];
        }
        asm volatile("s_waitcnt lgkmcnt(0)" ::: "memory");
        __builtin_amdgcn_s_barrier();
        const int tok = inputs[bb * S_ + mt];
        float m = -INFINITY, s = 0.f, mv = -INFINITY, tv = -INFINITY;
        int mi = 0x7fffffff;
#pragma unroll
        for (int q = 0; q < 8; ++q) {
            const int vl = sub * 8 + q, v = v0 + vl;
            float x = slds[bb][vl] + bo[q];
            float nm = fmaxf(m, x);
            s = s * __expf(m - nm) + __expf(x - nm);
            m = nm;
            if (x > mv) { mv = x; mi = v; }
            if (v == tok) tv = x;
        }
#pragma unroll
        for (int off = 1; off < 16; off <<= 1) {
            float cm = __shfl_xor(m, off), cs = __shfl_xor(s, off);
            float cmv = __shfl_xor(mv, off), ctv = __shfl_xor(tv, off);
            int cmi = __shfl_xor(mi, off);
            float nm = fmaxf(m, cm);
            s = s * __expf(m - nm) + cs * __expf(cm - nm);
            m = nm;
            if (cmv > mv || (cmv == mv && cmi < mi)) { mv = cmv; mi = cmi; }
            tv = fmaxf(tv, ctv);
        }
        if (sub == 0) {
            float* o = sp + ((size_t)(mt * 32 + bb) * NGB + blockIdx.x) * 5;
            o[0] = m; o[1] = s; o[2] = mv; o[3] = (float)mi; o[4] = tv;
        }
        asm volatile("s_waitcnt vmcnt(0)" ::: "memory");   // this wave's stage loads done
        __builtin_amdgcn_s_barrier();                      // all waves' chunks in LDS
    }
}

// ---------------- merge 250 tile-partials per row -> symbols + per-row logp ---------
__global__ __launch_bounds__(256) void k_merge(const float* __restrict__ sp,
                                               float* __restrict__ out,
                                               float* __restrict__ lossbuf) {
    const int tid = threadIdx.x;
    const int mi16 = tid >> 4, l16 = tid & 15;
    const int m = blockIdx.x * 16 + mi16;
    float mm = -INFINITY, s = 0.f, mv = -INFINITY, tv = -INFINITY;
    int ai = 0x7fffffff;
    for (int i = l16; i < NGB; i += 16) {
        const float* o = sp + ((size_t)m * NGB + i) * 5;
        float cm = o[0], cs = o[1], cmv = o[2], ctv = o[4];
        int cmi = (int)o[3];
        float nm = fmaxf(mm, cm);
        s = s * expf(mm - nm) + cs * expf(cm - nm);
        mm = nm;
        if (cmv > mv || (cmv == mv && cmi < ai)) { mv = cmv; ai = cmi; }
        tv = fmaxf(tv, ctv);
    }
#pragma unroll
    for (int off = 1; off < 16; off <<= 1) {
        float cm = __shfl_xor(mm, off), cs = __shfl_xor(s, off);
        float cmv = __shfl_xor(mv, off), ctv = __shfl_xor(tv, off);
        int cmi = __shfl_xor(ai, off);
        float nm = fmaxf(mm, cm);
        s = s * expf(mm - nm) + cs * expf(cm - nm);
        mm = nm;
        if (cmv > mv || (cmv == mv && cmi < ai)) { mv = cmv; ai = cmi; }
        tv = fmaxf(tv, ctv);
    }
    if (l16 == 0) {
        const float logZ = mm + logf(s);
        const int t = m >> 5, b = m & 31;
        out[1 + b * S_ + t] = (float)ai;
        lossbuf[m] = tv - logZ;
    }
}

// ---------------- final: deterministic sum of per-row losses ----------------
__global__ __launch_bounds__(256) void k_sum(const float* __restrict__ lossbuf,
                                             float* __restrict__ out) {
    const int tid = threadIdx.x;
    float a = 0.f;
    for (int i = tid; i < B_ * S_; i += 256) a += lossbuf[i];
    __shared__ float red[256];
    red[tid] = a;
    __syncthreads();
    for (int off = 128; off > 0; off >>= 1) {
        if (tid < off) red[tid] += red[tid + off];
        __syncthreads();
    }
    if (tid == 0) out[0] = -red[0] / (float)B_;
}

extern "C" void kernel_launch(void* const* d_in, const int* in_sizes, int n_in,
                              void* d_out, int out_size, void* d_ws, size_t ws_size,
                              hipStream_t stream) {
    const int*   inputs = (const int*)d_in[0];
    const float* h0     = (const float*)d_in[3];
    const float* c0     = (const float*)d_in[4];
    const float* emb    = (const float*)d_in[5];
    const float* W_ih   = (const float*)d_in[6];
    const float* W_hh   = (const float*)d_in[7];
    const float* b_ih   = (const float*)d_in[8];
    const float* b_hh   = (const float*)d_in[9];
    const float* W_out  = (const float*)d_in[10];
    const float* b_out  = (const float*)d_in[11];
    float* out = (float*)d_out;

    char* p = (char*)d_ws;
    auto alloc = [&](size_t bytes) { char* r = p; p += (bytes + 255) & ~255ull; return r; };
    float* lossbuf  = (float*)alloc((size_t)B_ * S_ * 4);
    int*   flags    = (int*)alloc(64 * 32 * 4);
    float* sp       = (float*)alloc((size_t)B_ * S_ * NGB * 5 * 4);          // 20.5 MB
    us* A1  = (us*)alloc((size_t)(S_ + 1) * 16384 * 2);
    us* A2  = (us*)alloc((size_t)(S_ + 1) * 16384 * 2);
    us* A3  = (us*)alloc((size_t)(S_ + 1) * 16384 * 2);
    us* B1f = (us*)alloc((size_t)RBLK * 16384 * 2);                          // 2.1 MB
    us* B2f = (us*)alloc((size_t)RBLK * 16384 * 2);
    us* B3f = (us*)alloc((size_t)RBLK * 16384 * 2);
    float* XW = (float*)alloc((size_t)S_ * B_ * G4_ * 4);                    // 33.5 MB

    (void)hipMemsetAsync(flags, 0, 64 * 32 * 4, stream);
    k_whh3<<<(RBLK * 2 * 16 * 64) / 256, 256, 0, stream>>>(W_hh, B1f, B2f, B3f);
    k_xw<<<dim3(8, S_), 256, 0, stream>>>(inputs, emb, W_ih, b_ih, b_hh, XW);
    k_recur<<<RBLK, 256, 0, stream>>>(h0, c0, B1f, B2f, B3f, XW, A1, A2, A3, flags);
    k_gemm<<<NGB, 512, 0, stream>>>(inputs, A1, A2, W_out, b_out, sp);
    k_merge<<<(B_ * S_) / 16, 256, 0, stream>>>(sp, out, lossbuf);
    k_sum<<<1, 256, 0, stream>>>(lossbuf, out);
}